// Round 14
// baseline (126.068 us; speedup 1.0000x reference)
//
#include <hip/hip_runtime.h>
#include <stdint.h>

#define NT 5
#define NC 32
#define NH 4
#define HW 4096             // 64*64
#define NPIX 40960          // (b*t)*HW
#define QS 0.51006972789f   // (1/sqrt(8)) * log2(e): fold scale + ln->log2 into q
#define EBIAS 12.0f         // softmax shift: p = 2^(e-EBIAS); cancels in acc/l

typedef _Float16 half_t;
typedef half_t h2 __attribute__((ext_vector_type(2)));

static __device__ __forceinline__ h2 as_h2(uint32_t u) {
  union { uint32_t u; h2 h; } c; c.u = u; return c.h;
}
static __device__ __forceinline__ uint32_t pack_h2(float a, float b) {
  union { h2 h; uint32_t u; } c;
  c.h.x = (half_t)a; c.h.y = (half_t)b;
  return c.u;
}

#if __has_builtin(__builtin_amdgcn_exp2f)
#define EXP2(x) __builtin_amdgcn_exp2f(x)
#else
#define EXP2(x) exp2f(x)
#endif

// dot8 with accumulator initialized at -EBIAS: e = q.k - 12, rides for free.
static __device__ __forceinline__ float dot8b(const uint4& a, const uint4& b) {
#if __has_builtin(__builtin_amdgcn_fdot2)
  float c = -EBIAS;
  c = __builtin_amdgcn_fdot2(as_h2(a.x), as_h2(b.x), c, false);
  c = __builtin_amdgcn_fdot2(as_h2(a.y), as_h2(b.y), c, false);
  c = __builtin_amdgcn_fdot2(as_h2(a.z), as_h2(b.z), c, false);
  c = __builtin_amdgcn_fdot2(as_h2(a.w), as_h2(b.w), c, false);
  return c;
#else
  const h2 a0 = as_h2(a.x), a1 = as_h2(a.y), a2 = as_h2(a.z), a3 = as_h2(a.w);
  const h2 b0 = as_h2(b.x), b1 = as_h2(b.y), b2 = as_h2(b.z), b3 = as_h2(b.w);
  float c = -EBIAS;
  c = fmaf((float)a0.x, (float)b0.x, c);
  c = fmaf((float)a0.y, (float)b0.y, c);
  c = fmaf((float)a1.x, (float)b1.x, c);
  c = fmaf((float)a1.y, (float)b1.y, c);
  c = fmaf((float)a2.x, (float)b2.x, c);
  c = fmaf((float)a2.y, (float)b2.y, c);
  c = fmaf((float)a3.x, (float)b3.x, c);
  c = fmaf((float)a3.y, (float)b3.y, c);
  return c;
#endif
}

// ---------------- Kernel A: QKV projection (R13, unchanged) -----------------
// Split per (head x output-quad): dim3(160,8) -> 1280 blocks, 20 waves/CU.
__global__ __launch_bounds__(256) void qkv_kernel(
    const float* __restrict__ x,
    const float* __restrict__ Wq, const float* __restrict__ Wk,
    const float* __restrict__ Wv,
    uint2* __restrict__ qf, uint2* __restrict__ kf, uint2* __restrict__ vf)
{
  const int p   = blockIdx.x * 256 + threadIdx.x;   // 0..40959
  const int by  = blockIdx.y;                       // 0..7
  const int h   = by >> 1;
  const int jg  = by & 1;
  const int bt  = p >> 12;
  const int pix = p & 4095;

  const float* xp = x + (size_t)bt * (NC * HW) + pix;
  float xc[NC];
  #pragma unroll
  for (int c = 0; c < NC; ++c) xc[c] = xp[(size_t)c * HW];

  float qv[4], kv4[4], vv4[4];
  #pragma unroll
  for (int j = 0; j < 4; ++j) {
    const int o = h * 8 + jg * 4 + j;
    float aq = 0.f, ak = 0.f, av = 0.f;
    #pragma unroll
    for (int c = 0; c < NC; ++c) {
      const float xv = xc[c];
      aq = fmaf(xv, Wq[o * NC + c], aq);
      ak = fmaf(xv, Wk[o * NC + c], ak);
      av = fmaf(xv, Wv[o * NC + c], av);
    }
    qv[j] = aq * QS; kv4[j] = ak; vv4[j] = av;
  }
  const size_t base = (((size_t)bt * NH + h) * HW + pix) * 2 + jg;
  uint2 qq, kk, vv;
  qq.x = pack_h2(qv[0], qv[1]);  qq.y = pack_h2(qv[2], qv[3]);
  kk.x = pack_h2(kv4[0], kv4[1]); kk.y = pack_h2(kv4[2], kv4[3]);
  vv.x = pack_h2(vv4[0], vv4[1]); vv.y = pack_h2(vv4[2], vv4[3]);
  qf[base] = qq;
  kf[base] = kk;
  vf[base] = vv;
}

// ---------------- Kernel B: neighborhood attention --------------------------
// R11/R13 body; ONLY change: u-loop `#pragma unroll 2` (was unroll 1) so the
// scheduler can hoist the next row's ds_reads across the current row's math.
template <int R, int D>
static __device__ __forceinline__ void attn_body(
    int b, int t, int h, int s, int yb,
    const uint4* __restrict__ qf, const uint4* __restrict__ kf,
    const uint4* __restrict__ vf,
    uint4* __restrict__ pa, float* __restrict__ pl,
    uint4* __restrict__ k_lds, uint4* __restrict__ v_lds)
{
  constexpr int LS    = 2 * R + 1;
  constexpr int NROWS = 8 + 2 * R;        // staged key rows (step D)
  const int tid  = threadIdx.x;
  const int w    = tid >> 6;              // wave 0..3
  const int lane = tid & 63;

  // first query row of this block (D2: yb&1 = row parity, 8 same-parity rows)
  const int y0 = (D == 1) ? (yb * 8) : ((yb & 1) + 2 * ((yb >> 1) * 8));

  // ---- stage NROWS full-width K,V rows into LDS (coalesced) ----
  const uint4* kg = kf + (size_t)((b * NT + s) * NH + h) * HW;
  const uint4* vg = vf + (size_t)((b * NT + s) * NH + h) * HW;
  for (int idx = tid; idx < NROWS * 64; idx += 256) {
    const int r  = idx >> 6, xs = idx & 63;
    int ys = y0 + (r - R) * D;
    ys = ys < 0 ? 0 : (ys > 63 ? 63 : ys);          // clamp; masked at compute
    const int pos = (D == 1) ? xs : ((xs & 1) * 32 + (xs >> 1));
    k_lds[r * 64 + pos] = kg[ys * 64 + xs];
    v_lds[r * 64 + pos] = vg[ys * 64 + xs];
  }
  __syncthreads();

  const int xp = lane >> 5;                          // D2 x-parity
  const int cb = (D == 1) ? lane : (lane & 31);      // compressed x
  const int x  = (D == 1) ? lane : (2 * (lane & 31) + xp);
  const int yA = y0 + 2 * w * D;
  const int yB = yA + D;
  const int pixA = yA * 64 + x, pixB = yB * 64 + x;

  const uint4* qp = qf + (size_t)((b * NT + t) * NH + h) * HW;
  const uint4 qA = qp[pixA];
  const uint4 qB = qp[pixB];

  float lA = 0.f, lB = 0.f;
  h2 aA[4], aB[4];
  const h2 z2 = { (half_t)0.f, (half_t)0.f };
  #pragma unroll
  for (int i = 0; i < 4; ++i) { aA[i] = z2; aB[i] = z2; }

  #pragma unroll 2
  for (int u = 0; u <= LS; ++u) {                    // key-row sweep, pair-shared
    const bool okA = (u < LS) && ((unsigned)(yA + (u - R) * D) < 64u);
    const bool okB = (u > 0)  && ((unsigned)(yB + (u - 1 - R) * D) < 64u);
    if (!(okA || okB)) continue;                     // wave-uniform skip
    const float mA = okA ? 1.f : 0.f, mB = okB ? 1.f : 0.f;
    const uint4* kr = k_lds + (2 * w + u) * 64;
    const uint4* vr = v_lds + (2 * w + u) * 64;
    #pragma unroll
    for (int dx = -R; dx <= R; ++dx) {
      const int  cx  = cb + dx;
      const bool okx = (unsigned)cx < (D == 1 ? 64u : 32u);
      const int  cc  = okx ? cx : 0;
      const int  pos = (D == 1) ? cc : (xp * 32 + cc);
      const uint4 kk = kr[pos];
      const uint4 vv = vr[pos];
      const h2 w0 = as_h2(vv.x), w1 = as_h2(vv.y), w2 = as_h2(vv.z), w3 = as_h2(vv.w);
      const float eA = dot8b(qA, kk);                // e - EBIAS, bias free
      const float eB = dot8b(qB, kk);
      const float pA = (okx ? mA : 0.f) * EXP2(eA);
      const float pB = (okx ? mB : 0.f) * EXP2(eB);
      lA += pA; lB += pB;
      const half_t pAh = (half_t)pA, pBh = (half_t)pB;
      const h2 pA2 = { pAh, pAh }, pB2 = { pBh, pBh };
      aA[0] += pA2 * w0; aA[1] += pA2 * w1; aA[2] += pA2 * w2; aA[3] += pA2 * w3;
      aB[0] += pB2 * w0; aB[1] += pB2 * w1; aB[2] += pB2 * w2; aB[3] += pB2 * w3;
    }
  }

  // ---- store frame-partials: pa/pl [s][h][btpix], each written once ----
  const size_t plane = (size_t)(s * NH + h) * NPIX + (size_t)(b * NT + t) * HW;
  union { h2 hh[4]; uint4 u; } cA, cB;
  #pragma unroll
  for (int i = 0; i < 4; ++i) { cA.hh[i] = aA[i]; cB.hh[i] = aB[i]; }
  pa[plane + pixA] = cA.u;
  pa[plane + pixB] = cB.u;
  pl[plane + pixA] = lA;
  pl[plane + pixB] = lB;
}

__global__ __launch_bounds__(256) void attn_kernel(
    const uint4* __restrict__ qf, const uint4* __restrict__ kf,
    const uint4* __restrict__ vf, uint4* __restrict__ pa, float* __restrict__ pl)
{
  __shared__ uint4 k_lds[16 * 64];   // 16 KB
  __shared__ uint4 v_lds[16 * 64];   // 16 KB
  const int bid = blockIdx.x;        // 1600 = 10(bt) * 5(s) * 8(yb) * 4(h)
  const int h   = bid & 3;           // head in low bits -> R3/R4 mix per CU
  int r = bid >> 2;
  const int yb = r & 7; r >>= 3;
  const int s  = r % 5;
  const int bt = r / 5;
  const int t = bt % NT, b = bt / NT;
  if      (h == 0) attn_body<3, 1>(b, t, 0, s, yb, qf, kf, vf, pa, pl, k_lds, v_lds);
  else if (h == 1) attn_body<3, 2>(b, t, 1, s, yb, qf, kf, vf, pa, pl, k_lds, v_lds);
  else if (h == 2) attn_body<4, 1>(b, t, 2, s, yb, qf, kf, vf, pa, pl, k_lds, v_lds);
  else             attn_body<4, 2>(b, t, 3, s, yb, qf, kf, vf, pa, pl, k_lds, v_lds);
}

// ---------------- Kernel C: reduce + normalize + Wo + residual --------------
// Block = 256 thr = 64 pixels x 4 waves. Wave h reduces head h for the 64
// pixels (1x loads, was 4x in R13), normalized oc through padded LDS
// (stride 33, conflict-free), then wave og computes its 8 out-channels.
__global__ __launch_bounds__(256) void proj_kernel(
    const uint4* __restrict__ pa, const float* __restrict__ pl,
    const float* __restrict__ x, const float* __restrict__ Wo,
    float* __restrict__ out)
{
  __shared__ float smem[64 * 33];                   // 8.4 KB, +1 pad
  const int tid  = threadIdx.x;
  const int pixl = tid & 63;
  const int hg   = tid >> 6;                        // head for reduce, og for out
  const int p    = blockIdx.x * 64 + pixl;          // btpix 0..40959
  const int bt   = p >> 12;
  const int pix  = p & 4095;

  float a[8], l = 0.f;
  #pragma unroll
  for (int i = 0; i < 8; ++i) a[i] = 0.f;
  #pragma unroll
  for (int s = 0; s < NT; ++s) {
    const size_t plane = (size_t)(s * NH + hg) * NPIX + p;
    const uint4 v = pa[plane];
    l += pl[plane];
    const h2 v0 = as_h2(v.x), v1 = as_h2(v.y), v2 = as_h2(v.z), v3 = as_h2(v.w);
    a[0] += (float)v0.x; a[1] += (float)v0.y;
    a[2] += (float)v1.x; a[3] += (float)v1.y;
    a[4] += (float)v2.x; a[5] += (float)v2.y;
    a[6] += (float)v3.x; a[7] += (float)v3.y;
  }
  const float inv = 1.0f / l;
  #pragma unroll
  for (int i = 0; i < 8; ++i) smem[pixl * 33 + hg * 8 + i] = a[i] * inv;
  __syncthreads();

  float oc[32];
  #pragma unroll
  for (int c = 0; c < NC; ++c) oc[c] = smem[pixl * 33 + c];

  const float* xpt = x + (size_t)bt * (NC * HW) + pix;
  float* yp = out + (size_t)bt * (NC * HW) + pix;
  #pragma unroll
  for (int oo = 0; oo < 8; ++oo) {
    const int o = hg * 8 + oo;
    float acc = xpt[(size_t)o * HW];                // residual
    #pragma unroll
    for (int c = 0; c < NC; ++c)
      acc = fmaf(oc[c], Wo[o * NC + c], acc);
    yp[(size_t)o * HW] = acc;
  }
}

extern "C" void kernel_launch(void* const* d_in, const int* in_sizes, int n_in,
                              void* d_out, int out_size, void* d_ws, size_t ws_size,
                              hipStream_t stream)
{
  const float* x  = (const float*)d_in[0];
  const float* Wq = (const float*)d_in[1];
  const float* Wk = (const float*)d_in[2];
  const float* Wv = (const float*)d_in[3];
  const float* Wo = (const float*)d_in[4];

  char* ws = (char*)d_ws;
  uint2* qf = (uint2*)ws;                           //  2,621,440 B
  uint2* kf = (uint2*)(ws + 2621440);               //  2,621,440 B
  uint2* vf = (uint2*)(ws + 2 * 2621440);           //  2,621,440 B
  uint4* pa = (uint4*)(ws + 3 * 2621440);           // 13,107,200 B (fp16x8 partials)
  float* pl = (float*)(ws + 3 * 2621440 + 13107200); // 3,276,800 B (fp32 l)

  qkv_kernel<<<dim3(160, 8), 256, 0, stream>>>(x, Wq, Wk, Wv, qf, kf, vf);
  attn_kernel<<<1600, 256, 0, stream>>>((const uint4*)qf, (const uint4*)kf,
                                        (const uint4*)vf, pa, pl);
  proj_kernel<<<640, 256, 0, stream>>>(pa, pl, x, Wo, (float*)d_out);
}

// Round 15
// 125.788 us; speedup vs baseline: 1.0022x; 1.0022x over previous
//
#include <hip/hip_runtime.h>
#include <stdint.h>

#define NT 5
#define NC 32
#define NH 4
#define HW 4096             // 64*64
#define NPIX 40960          // (b*t)*HW
#define QS 0.51006972789f   // (1/sqrt(8)) * log2(e): fold scale + ln->log2 into q
#define EBIAS 12.0f         // softmax shift: p = 2^(e-EBIAS); cancels in acc/l

typedef _Float16 half_t;
typedef half_t h2 __attribute__((ext_vector_type(2)));

static __device__ __forceinline__ h2 as_h2(uint32_t u) {
  union { uint32_t u; h2 h; } c; c.u = u; return c.h;
}
static __device__ __forceinline__ uint32_t pack_h2(float a, float b) {
  union { h2 h; uint32_t u; } c;
  c.h.x = (half_t)a; c.h.y = (half_t)b;
  return c.u;
}

#if __has_builtin(__builtin_amdgcn_exp2f)
#define EXP2(x) __builtin_amdgcn_exp2f(x)
#else
#define EXP2(x) exp2f(x)
#endif

// dot8 with accumulator initialized at -EBIAS: e = q.k - 12, rides for free.
static __device__ __forceinline__ float dot8b(const uint4& a, const uint4& b) {
#if __has_builtin(__builtin_amdgcn_fdot2)
  float c = -EBIAS;
  c = __builtin_amdgcn_fdot2(as_h2(a.x), as_h2(b.x), c, false);
  c = __builtin_amdgcn_fdot2(as_h2(a.y), as_h2(b.y), c, false);
  c = __builtin_amdgcn_fdot2(as_h2(a.z), as_h2(b.z), c, false);
  c = __builtin_amdgcn_fdot2(as_h2(a.w), as_h2(b.w), c, false);
  return c;
#else
  const h2 a0 = as_h2(a.x), a1 = as_h2(a.y), a2 = as_h2(a.z), a3 = as_h2(a.w);
  const h2 b0 = as_h2(b.x), b1 = as_h2(b.y), b2 = as_h2(b.z), b3 = as_h2(b.w);
  float c = -EBIAS;
  c = fmaf((float)a0.x, (float)b0.x, c);
  c = fmaf((float)a0.y, (float)b0.y, c);
  c = fmaf((float)a1.x, (float)b1.x, c);
  c = fmaf((float)a1.y, (float)b1.y, c);
  c = fmaf((float)a2.x, (float)b2.x, c);
  c = fmaf((float)a2.y, (float)b2.y, c);
  c = fmaf((float)a3.x, (float)b3.x, c);
  c = fmaf((float)a3.y, (float)b3.y, c);
  return c;
#endif
}

// ---------------- Kernel A: QKV projection (R13 proven: ~12 us) -------------
// Split per (head x output-quad): dim3(160,8) -> 1280 blocks, 20 waves/CU.
__global__ __launch_bounds__(256) void qkv_kernel(
    const float* __restrict__ x,
    const float* __restrict__ Wq, const float* __restrict__ Wk,
    const float* __restrict__ Wv,
    uint2* __restrict__ qf, uint2* __restrict__ kf, uint2* __restrict__ vf)
{
  const int p   = blockIdx.x * 256 + threadIdx.x;   // 0..40959
  const int by  = blockIdx.y;                       // 0..7
  const int h   = by >> 1;
  const int jg  = by & 1;
  const int bt  = p >> 12;
  const int pix = p & 4095;

  const float* xp = x + (size_t)bt * (NC * HW) + pix;
  float xc[NC];
  #pragma unroll
  for (int c = 0; c < NC; ++c) xc[c] = xp[(size_t)c * HW];

  float qv[4], kv4[4], vv4[4];
  #pragma unroll
  for (int j = 0; j < 4; ++j) {
    const int o = h * 8 + jg * 4 + j;
    float aq = 0.f, ak = 0.f, av = 0.f;
    #pragma unroll
    for (int c = 0; c < NC; ++c) {
      const float xv = xc[c];
      aq = fmaf(xv, Wq[o * NC + c], aq);
      ak = fmaf(xv, Wk[o * NC + c], ak);
      av = fmaf(xv, Wv[o * NC + c], av);
    }
    qv[j] = aq * QS; kv4[j] = ak; vv4[j] = av;
  }
  const size_t base = (((size_t)bt * NH + h) * HW + pix) * 2 + jg;
  uint2 qq, kk, vv;
  qq.x = pack_h2(qv[0], qv[1]);  qq.y = pack_h2(qv[2], qv[3]);
  kk.x = pack_h2(kv4[0], kv4[1]); kk.y = pack_h2(kv4[2], kv4[3]);
  vv.x = pack_h2(vv4[0], vv4[1]); vv.y = pack_h2(vv4[2], vv4[3]);
  qf[base] = qq;
  kf[base] = kk;
  vf[base] = vv;
}

// ---------------- Kernel B: neighborhood attention (R12 proven shape) -------
// Block = 512 thr = 8 waves covering 16 query rows; wave w owns the vertical
// query pair (rows 2w, 2w+1 in compressed space) sharing the key-row sweep.
// 48 KB LDS -> 3 blocks/CU = 24 waves/CU; grid 800 vs capacity 768 (1.04 gen).
template <int R, int D>
static __device__ __forceinline__ void attn_body(
    int b, int t, int h, int s, int yb,
    const uint4* __restrict__ qf, const uint4* __restrict__ kf,
    const uint4* __restrict__ vf,
    uint4* __restrict__ pa, float* __restrict__ pl,
    uint4* __restrict__ k_lds, uint4* __restrict__ v_lds)
{
  constexpr int LS    = 2 * R + 1;
  constexpr int NROWS = 16 + 2 * R;       // staged key rows (step D)
  const int tid  = threadIdx.x;
  const int w    = tid >> 6;              // wave 0..7
  const int lane = tid & 63;

  // first query row of this block (D2: yb&1 = row parity, 16 same-parity rows)
  const int y0 = (D == 1) ? (yb * 16) : ((yb & 1) + 2 * ((yb >> 1) * 16));

  // ---- stage NROWS full-width K,V rows into LDS (coalesced) ----
  const uint4* kg = kf + (size_t)((b * NT + s) * NH + h) * HW;
  const uint4* vg = vf + (size_t)((b * NT + s) * NH + h) * HW;
  for (int idx = tid; idx < NROWS * 64; idx += 512) {
    const int r  = idx >> 6, xs = idx & 63;
    int ys = y0 + (r - R) * D;
    ys = ys < 0 ? 0 : (ys > 63 ? 63 : ys);          // clamp; masked at compute
    const int pos = (D == 1) ? xs : ((xs & 1) * 32 + (xs >> 1));
    k_lds[r * 64 + pos] = kg[ys * 64 + xs];
    v_lds[r * 64 + pos] = vg[ys * 64 + xs];
  }
  __syncthreads();

  const int xp = lane >> 5;                          // D2 x-parity
  const int cb = (D == 1) ? lane : (lane & 31);      // compressed x
  const int x  = (D == 1) ? lane : (2 * (lane & 31) + xp);
  const int yA = y0 + 2 * w * D;
  const int yB = yA + D;
  const int pixA = yA * 64 + x, pixB = yB * 64 + x;

  const uint4* qp = qf + (size_t)((b * NT + t) * NH + h) * HW;
  const uint4 qA = qp[pixA];
  const uint4 qB = qp[pixB];

  float lA = 0.f, lB = 0.f;
  h2 aA[4], aB[4];
  const h2 z2 = { (half_t)0.f, (half_t)0.f };
  #pragma unroll
  for (int i = 0; i < 4; ++i) { aA[i] = z2; aB[i] = z2; }

  #pragma unroll 1
  for (int u = 0; u <= LS; ++u) {                    // key-row sweep, pair-shared
    const bool okA = (u < LS) && ((unsigned)(yA + (u - R) * D) < 64u);
    const bool okB = (u > 0)  && ((unsigned)(yB + (u - 1 - R) * D) < 64u);
    if (!(okA || okB)) continue;                     // wave-uniform skip
    const float mA = okA ? 1.f : 0.f, mB = okB ? 1.f : 0.f;
    const uint4* kr = k_lds + (2 * w + u) * 64;
    const uint4* vr = v_lds + (2 * w + u) * 64;
    #pragma unroll
    for (int dx = -R; dx <= R; ++dx) {
      const int  cx  = cb + dx;
      const bool okx = (unsigned)cx < (D == 1 ? 64u : 32u);
      const int  cc  = okx ? cx : 0;
      const int  pos = (D == 1) ? cc : (xp * 32 + cc);
      const uint4 kk = kr[pos];
      const uint4 vv = vr[pos];
      const h2 w0 = as_h2(vv.x), w1 = as_h2(vv.y), w2 = as_h2(vv.z), w3 = as_h2(vv.w);
      const float eA = dot8b(qA, kk);                // e - EBIAS, bias free
      const float eB = dot8b(qB, kk);
      const float pA = (okx ? mA : 0.f) * EXP2(eA);
      const float pB = (okx ? mB : 0.f) * EXP2(eB);
      lA += pA; lB += pB;
      const half_t pAh = (half_t)pA, pBh = (half_t)pB;
      const h2 pA2 = { pAh, pAh }, pB2 = { pBh, pBh };
      aA[0] += pA2 * w0; aA[1] += pA2 * w1; aA[2] += pA2 * w2; aA[3] += pA2 * w3;
      aB[0] += pB2 * w0; aB[1] += pB2 * w1; aB[2] += pB2 * w2; aB[3] += pB2 * w3;
    }
  }

  // ---- store frame-partials: pa/pl [s][h][btpix], each written once ----
  const size_t plane = (size_t)(s * NH + h) * NPIX + (size_t)(b * NT + t) * HW;
  union { h2 hh[4]; uint4 u; } cA, cB;
  #pragma unroll
  for (int i = 0; i < 4; ++i) { cA.hh[i] = aA[i]; cB.hh[i] = aB[i]; }
  pa[plane + pixA] = cA.u;
  pa[plane + pixB] = cB.u;
  pl[plane + pixA] = lA;
  pl[plane + pixB] = lB;
}

__global__ __launch_bounds__(512) void attn_kernel(
    const uint4* __restrict__ qf, const uint4* __restrict__ kf,
    const uint4* __restrict__ vf, uint4* __restrict__ pa, float* __restrict__ pl)
{
  __shared__ uint4 k_lds[24 * 64];   // 24 KB (16+2*4 rows max)
  __shared__ uint4 v_lds[24 * 64];   // 24 KB
  const int bid = blockIdx.x;        // 800 = 10(bt) * 5(s) * 4(yb) * 4(h)
  const int h   = bid & 3;           // head in low bits -> R3/R4 mix per CU
  int r = bid >> 2;
  const int yb = r & 3; r >>= 2;
  const int s  = r % 5;
  const int bt = r / 5;
  const int t = bt % NT, b = bt / NT;
  if      (h == 0) attn_body<3, 1>(b, t, 0, s, yb, qf, kf, vf, pa, pl, k_lds, v_lds);
  else if (h == 1) attn_body<3, 2>(b, t, 1, s, yb, qf, kf, vf, pa, pl, k_lds, v_lds);
  else if (h == 2) attn_body<4, 1>(b, t, 2, s, yb, qf, kf, vf, pa, pl, k_lds, v_lds);
  else             attn_body<4, 2>(b, t, 3, s, yb, qf, kf, vf, pa, pl, k_lds, v_lds);
}

// ---------------- Kernel C: reduce + normalize + Wo + residual (R13: ~13us) -
// Split per out-channel-group og (8 channels): dim3(160,4) -> 640 blocks,
// 10 waves/CU. Each thread redoes the 20-load reduce (L2-resident re-read).
__global__ __launch_bounds__(256) void proj_kernel(
    const uint4* __restrict__ pa, const float* __restrict__ pl,
    const float* __restrict__ x, const float* __restrict__ Wo,
    float* __restrict__ out)
{
  const int p   = blockIdx.x * 256 + threadIdx.x;   // btpix 0..40959
  const int og  = blockIdx.y;                       // 8 out-channels per og
  const int bt  = p >> 12;
  const int pix = p & 4095;

  float oc[32];
  #pragma unroll
  for (int h = 0; h < NH; ++h) {
    float a[8], l = 0.f;
    #pragma unroll
    for (int i = 0; i < 8; ++i) a[i] = 0.f;
    #pragma unroll
    for (int s = 0; s < NT; ++s) {
      const size_t plane = (size_t)(s * NH + h) * NPIX + p;
      const uint4 v = pa[plane];
      l += pl[plane];
      const h2 v0 = as_h2(v.x), v1 = as_h2(v.y), v2 = as_h2(v.z), v3 = as_h2(v.w);
      a[0] += (float)v0.x; a[1] += (float)v0.y;
      a[2] += (float)v1.x; a[3] += (float)v1.y;
      a[4] += (float)v2.x; a[5] += (float)v2.y;
      a[6] += (float)v3.x; a[7] += (float)v3.y;
    }
    const float inv = 1.0f / l;
    #pragma unroll
    for (int i = 0; i < 8; ++i) oc[h * 8 + i] = a[i] * inv;
  }

  const float* xpt = x + (size_t)bt * (NC * HW) + pix;
  float* yp = out + (size_t)bt * (NC * HW) + pix;
  #pragma unroll
  for (int oo = 0; oo < 8; ++oo) {
    const int o = og * 8 + oo;
    float acc = xpt[(size_t)o * HW];                // residual
    #pragma unroll
    for (int c = 0; c < NC; ++c)
      acc = fmaf(oc[c], Wo[o * NC + c], acc);
    yp[(size_t)o * HW] = acc;
  }
}

extern "C" void kernel_launch(void* const* d_in, const int* in_sizes, int n_in,
                              void* d_out, int out_size, void* d_ws, size_t ws_size,
                              hipStream_t stream)
{
  const float* x  = (const float*)d_in[0];
  const float* Wq = (const float*)d_in[1];
  const float* Wk = (const float*)d_in[2];
  const float* Wv = (const float*)d_in[3];
  const float* Wo = (const float*)d_in[4];

  char* ws = (char*)d_ws;
  uint2* qf = (uint2*)ws;                           //  2,621,440 B
  uint2* kf = (uint2*)(ws + 2621440);               //  2,621,440 B
  uint2* vf = (uint2*)(ws + 2 * 2621440);           //  2,621,440 B
  uint4* pa = (uint4*)(ws + 3 * 2621440);           // 13,107,200 B (fp16x8 partials)
  float* pl = (float*)(ws + 3 * 2621440 + 13107200); // 3,276,800 B (fp32 l)

  qkv_kernel<<<dim3(160, 8), 256, 0, stream>>>(x, Wq, Wk, Wv, qf, kf, vf);
  attn_kernel<<<800, 512, 0, stream>>>((const uint4*)qf, (const uint4*)kf,
                                       (const uint4*)vf, pa, pl);
  proj_kernel<<<dim3(160, 4), 256, 0, stream>>>(pa, pl, x, Wo, (float*)d_out);
}

// Round 16
// 117.594 us; speedup vs baseline: 1.0721x; 1.0697x over previous
//
#include <hip/hip_runtime.h>
#include <stdint.h>

#define NT 5
#define NC 32
#define NH 4
#define HW 4096             // 64*64
#define NPIX 40960          // (b*t)*HW
#define QS 0.51006972789f   // (1/sqrt(8)) * log2(e): fold scale + ln->log2 into q
#define EBIAS 12.0f         // softmax shift: p = 2^(e-EBIAS); cancels in acc/l
#define NINF (-__builtin_inff())

typedef _Float16 half_t;
typedef half_t h2 __attribute__((ext_vector_type(2)));

static __device__ __forceinline__ h2 as_h2(uint32_t u) {
  union { uint32_t u; h2 h; } c; c.u = u; return c.h;
}
static __device__ __forceinline__ uint32_t pack_h2(float a, float b) {
  union { h2 h; uint32_t u; } c;
  c.h.x = (half_t)a; c.h.y = (half_t)b;
  return c.u;
}

#if __has_builtin(__builtin_amdgcn_exp2f)
#define EXP2(x) __builtin_amdgcn_exp2f(x)
#else
#define EXP2(x) exp2f(x)
#endif

// dot8 with runtime init accumulator (carries -EBIAS and the 0/-inf masks free)
static __device__ __forceinline__ float dot8i(const uint4& a, const uint4& b, float c) {
#if __has_builtin(__builtin_amdgcn_fdot2)
  c = __builtin_amdgcn_fdot2(as_h2(a.x), as_h2(b.x), c, false);
  c = __builtin_amdgcn_fdot2(as_h2(a.y), as_h2(b.y), c, false);
  c = __builtin_amdgcn_fdot2(as_h2(a.z), as_h2(b.z), c, false);
  c = __builtin_amdgcn_fdot2(as_h2(a.w), as_h2(b.w), c, false);
  return c;
#else
  const h2 a0 = as_h2(a.x), a1 = as_h2(a.y), a2 = as_h2(a.z), a3 = as_h2(a.w);
  const h2 b0 = as_h2(b.x), b1 = as_h2(b.y), b2 = as_h2(b.z), b3 = as_h2(b.w);
  c = fmaf((float)a0.x, (float)b0.x, c);
  c = fmaf((float)a0.y, (float)b0.y, c);
  c = fmaf((float)a1.x, (float)b1.x, c);
  c = fmaf((float)a1.y, (float)b1.y, c);
  c = fmaf((float)a2.x, (float)b2.x, c);
  c = fmaf((float)a2.y, (float)b2.y, c);
  c = fmaf((float)a3.x, (float)b3.x, c);
  c = fmaf((float)a3.y, (float)b3.y, c);
  return c;
#endif
}

// ---------------- Kernel A: QKV projection (R13 proven: ~12 us) -------------
// Split per (head x output-quad): dim3(160,8) -> 1280 blocks, 20 waves/CU.
__global__ __launch_bounds__(256) void qkv_kernel(
    const float* __restrict__ x,
    const float* __restrict__ Wq, const float* __restrict__ Wk,
    const float* __restrict__ Wv,
    uint2* __restrict__ qf, uint2* __restrict__ kf, uint2* __restrict__ vf)
{
  const int p   = blockIdx.x * 256 + threadIdx.x;   // 0..40959
  const int by  = blockIdx.y;                       // 0..7
  const int h   = by >> 1;
  const int jg  = by & 1;
  const int bt  = p >> 12;
  const int pix = p & 4095;

  const float* xp = x + (size_t)bt * (NC * HW) + pix;
  float xc[NC];
  #pragma unroll
  for (int c = 0; c < NC; ++c) xc[c] = xp[(size_t)c * HW];

  float qv[4], kv4[4], vv4[4];
  #pragma unroll
  for (int j = 0; j < 4; ++j) {
    const int o = h * 8 + jg * 4 + j;
    float aq = 0.f, ak = 0.f, av = 0.f;
    #pragma unroll
    for (int c = 0; c < NC; ++c) {
      const float xv = xc[c];
      aq = fmaf(xv, Wq[o * NC + c], aq);
      ak = fmaf(xv, Wk[o * NC + c], ak);
      av = fmaf(xv, Wv[o * NC + c], av);
    }
    qv[j] = aq * QS; kv4[j] = ak; vv4[j] = av;
  }
  const size_t base = (((size_t)bt * NH + h) * HW + pix) * 2 + jg;
  uint2 qq, kk, vv;
  qq.x = pack_h2(qv[0], qv[1]);  qq.y = pack_h2(qv[2], qv[3]);
  kk.x = pack_h2(kv4[0], kv4[1]); kk.y = pack_h2(kv4[2], kv4[3]);
  vv.x = pack_h2(vv4[0], vv4[1]); vv.y = pack_h2(vv4[2], vv4[3]);
  qf[base] = qq;
  kf[base] = kk;
  vf[base] = vv;
}

// ---------------- Kernel B: neighborhood attention --------------------------
// Proven 256-thr pair body + unroll 2; NEW: row/col masks folded into the
// dot init as -inf (exp2(-inf)=0) -> inner loop loses 2 cndmask + 2 mul.
template <int R, int D>
static __device__ __forceinline__ void attn_body(
    int b, int t, int h, int s, int yb,
    const uint4* __restrict__ qf, const uint4* __restrict__ kf,
    const uint4* __restrict__ vf,
    uint4* __restrict__ pa, float* __restrict__ pl,
    uint4* __restrict__ k_lds, uint4* __restrict__ v_lds)
{
  constexpr int LS    = 2 * R + 1;
  constexpr int NROWS = 8 + 2 * R;        // staged key rows (step D)
  const int tid  = threadIdx.x;
  const int w    = tid >> 6;              // wave 0..3
  const int lane = tid & 63;

  // first query row of this block (D2: yb&1 = row parity, 8 same-parity rows)
  const int y0 = (D == 1) ? (yb * 8) : ((yb & 1) + 2 * ((yb >> 1) * 8));

  // ---- stage NROWS full-width K,V rows into LDS (coalesced) ----
  const uint4* kg = kf + (size_t)((b * NT + s) * NH + h) * HW;
  const uint4* vg = vf + (size_t)((b * NT + s) * NH + h) * HW;
  for (int idx = tid; idx < NROWS * 64; idx += 256) {
    const int r  = idx >> 6, xs = idx & 63;
    int ys = y0 + (r - R) * D;
    ys = ys < 0 ? 0 : (ys > 63 ? 63 : ys);          // clamp; masked at compute
    const int pos = (D == 1) ? xs : ((xs & 1) * 32 + (xs >> 1));
    k_lds[r * 64 + pos] = kg[ys * 64 + xs];
    v_lds[r * 64 + pos] = vg[ys * 64 + xs];
  }
  __syncthreads();

  const int xp = lane >> 5;                          // D2 x-parity
  const int cb = (D == 1) ? lane : (lane & 31);      // compressed x
  const int x  = (D == 1) ? lane : (2 * (lane & 31) + xp);
  const int yA = y0 + 2 * w * D;
  const int yB = yA + D;
  const int pixA = yA * 64 + x, pixB = yB * 64 + x;

  const uint4* qp = qf + (size_t)((b * NT + t) * NH + h) * HW;
  const uint4 qA = qp[pixA];
  const uint4 qB = qp[pixB];

  float lA = 0.f, lB = 0.f;
  h2 aA[4], aB[4];
  const h2 z2 = { (half_t)0.f, (half_t)0.f };
  #pragma unroll
  for (int i = 0; i < 4; ++i) { aA[i] = z2; aB[i] = z2; }

  #pragma unroll 2
  for (int u = 0; u <= LS; ++u) {                    // key-row sweep, pair-shared
    const bool okA = (u < LS) && ((unsigned)(yA + (u - R) * D) < 64u);
    const bool okB = (u > 0)  && ((unsigned)(yB + (u - 1 - R) * D) < 64u);
    if (!(okA || okB)) continue;                     // wave-uniform skip
    const float biA = okA ? -EBIAS : NINF;           // row mask folded into dot
    const float biB = okB ? -EBIAS : NINF;
    const uint4* kr = k_lds + (2 * w + u) * 64;
    const uint4* vr = v_lds + (2 * w + u) * 64;
    #pragma unroll
    for (int dx = -R; dx <= R; ++dx) {
      const int  cx  = cb + dx;
      const bool okx = (unsigned)cx < (D == 1 ? 64u : 32u);
      const int  cc  = okx ? cx : 0;
      const int  pos = (D == 1) ? cc : (xp * 32 + cc);
      const uint4 kk = kr[pos];
      const uint4 vv = vr[pos];
      const h2 w0 = as_h2(vv.x), w1 = as_h2(vv.y), w2 = as_h2(vv.z), w3 = as_h2(vv.w);
      const float eo = okx ? 0.f : NINF;             // col mask, shared by pair
      const float pA = EXP2(dot8i(qA, kk, biA + eo));
      const float pB = EXP2(dot8i(qB, kk, biB + eo));
      lA += pA; lB += pB;
      const half_t pAh = (half_t)pA, pBh = (half_t)pB;
      const h2 pA2 = { pAh, pAh }, pB2 = { pBh, pBh };
      aA[0] += pA2 * w0; aA[1] += pA2 * w1; aA[2] += pA2 * w2; aA[3] += pA2 * w3;
      aB[0] += pB2 * w0; aB[1] += pB2 * w1; aB[2] += pB2 * w2; aB[3] += pB2 * w3;
    }
  }

  // ---- store frame-partials: pa/pl [s][h][btpix], each written once ----
  const size_t plane = (size_t)(s * NH + h) * NPIX + (size_t)(b * NT + t) * HW;
  union { h2 hh[4]; uint4 u; } cA, cB;
  #pragma unroll
  for (int i = 0; i < 4; ++i) { cA.hh[i] = aA[i]; cB.hh[i] = aB[i]; }
  pa[plane + pixA] = cA.u;
  pa[plane + pixB] = cB.u;
  pl[plane + pixA] = lA;
  pl[plane + pixB] = lB;
}

__global__ __launch_bounds__(256) void attn_kernel(
    const uint4* __restrict__ qf, const uint4* __restrict__ kf,
    const uint4* __restrict__ vf, uint4* __restrict__ pa, float* __restrict__ pl)
{
  __shared__ uint4 k_lds[16 * 64];   // 16 KB
  __shared__ uint4 v_lds[16 * 64];   // 16 KB
  const int bid = blockIdx.x;        // 1600 = 10(bt) * 5(s) * 8(yb) * 4(h)
  const int h   = bid & 3;           // head in low bits -> R3/R4 mix per CU
  int r = bid >> 2;
  const int yb = r & 7; r >>= 3;
  const int s  = r % 5;
  const int bt = r / 5;
  const int t = bt % NT, b = bt / NT;
  if      (h == 0) attn_body<3, 1>(b, t, 0, s, yb, qf, kf, vf, pa, pl, k_lds, v_lds);
  else if (h == 1) attn_body<3, 2>(b, t, 1, s, yb, qf, kf, vf, pa, pl, k_lds, v_lds);
  else if (h == 2) attn_body<4, 1>(b, t, 2, s, yb, qf, kf, vf, pa, pl, k_lds, v_lds);
  else             attn_body<4, 2>(b, t, 3, s, yb, qf, kf, vf, pa, pl, k_lds, v_lds);
}

// ---------------- Kernel C: reduce + normalize + Wo + residual (R13: ~13us) -
// Split per out-channel-group og (8 channels): dim3(160,4) -> 640 blocks,
// 10 waves/CU. Each thread redoes the 20-load reduce (L2-resident re-read).
__global__ __launch_bounds__(256) void proj_kernel(
    const uint4* __restrict__ pa, const float* __restrict__ pl,
    const float* __restrict__ x, const float* __restrict__ Wo,
    float* __restrict__ out)
{
  const int p   = blockIdx.x * 256 + threadIdx.x;   // btpix 0..40959
  const int og  = blockIdx.y;                       // 8 out-channels per og
  const int bt  = p >> 12;
  const int pix = p & 4095;

  float oc[32];
  #pragma unroll
  for (int h = 0; h < NH; ++h) {
    float a[8], l = 0.f;
    #pragma unroll
    for (int i = 0; i < 8; ++i) a[i] = 0.f;
    #pragma unroll
    for (int s = 0; s < NT; ++s) {
      const size_t plane = (size_t)(s * NH + h) * NPIX + p;
      const uint4 v = pa[plane];
      l += pl[plane];
      const h2 v0 = as_h2(v.x), v1 = as_h2(v.y), v2 = as_h2(v.z), v3 = as_h2(v.w);
      a[0] += (float)v0.x; a[1] += (float)v0.y;
      a[2] += (float)v1.x; a[3] += (float)v1.y;
      a[4] += (float)v2.x; a[5] += (float)v2.y;
      a[6] += (float)v3.x; a[7] += (float)v3.y;
    }
    const float inv = 1.0f / l;
    #pragma unroll
    for (int i = 0; i < 8; ++i) oc[h * 8 + i] = a[i] * inv;
  }

  const float* xpt = x + (size_t)bt * (NC * HW) + pix;
  float* yp = out + (size_t)bt * (NC * HW) + pix;
  #pragma unroll
  for (int oo = 0; oo < 8; ++oo) {
    const int o = og * 8 + oo;
    float acc = xpt[(size_t)o * HW];                // residual
    #pragma unroll
    for (int c = 0; c < NC; ++c)
      acc = fmaf(oc[c], Wo[o * NC + c], acc);
    yp[(size_t)o * HW] = acc;
  }
}

extern "C" void kernel_launch(void* const* d_in, const int* in_sizes, int n_in,
                              void* d_out, int out_size, void* d_ws, size_t ws_size,
                              hipStream_t stream)
{
  const float* x  = (const float*)d_in[0];
  const float* Wq = (const float*)d_in[1];
  const float* Wk = (const float*)d_in[2];
  const float* Wv = (const float*)d_in[3];
  const float* Wo = (const float*)d_in[4];

  char* ws = (char*)d_ws;
  uint2* qf = (uint2*)ws;                           //  2,621,440 B
  uint2* kf = (uint2*)(ws + 2621440);               //  2,621,440 B
  uint2* vf = (uint2*)(ws + 2 * 2621440);           //  2,621,440 B
  uint4* pa = (uint4*)(ws + 3 * 2621440);           // 13,107,200 B (fp16x8 partials)
  float* pl = (float*)(ws + 3 * 2621440 + 13107200); // 3,276,800 B (fp32 l)

  qkv_kernel<<<dim3(160, 8), 256, 0, stream>>>(x, Wq, Wk, Wv, qf, kf, vf);
  attn_kernel<<<1600, 256, 0, stream>>>((const uint4*)qf, (const uint4*)kf,
                                        (const uint4*)vf, pa, pl);
  proj_kernel<<<dim3(160, 4), 256, 0, stream>>>(pa, pl, x, Wo, (float*)d_out);
}